// Round 1
// baseline (687.970 us; speedup 1.0000x reference)
//
#include <hip/hip_runtime.h>
#include <cstdint>
#include <cstddef>

typedef unsigned short ushort_t;
typedef __attribute__((ext_vector_type(8))) __bf16 bf16x8;
typedef __attribute__((ext_vector_type(4))) float f32x4;

#define DEVINL __device__ __forceinline__

// fp32 -> bf16 round-to-nearest-even
DEVINL ushort_t f2bf(float f) {
  union { float f; unsigned u; } v; v.f = f;
  unsigned r = (v.u + 0x7fffu + ((v.u >> 16) & 1u)) >> 16;
  return (ushort_t)r;
}

DEVINL float wred_sum(float x) {
#pragma unroll
  for (int o = 32; o > 0; o >>= 1) x += __shfl_xor(x, o, 64);
  return x;
}
DEVINL float wred_max(float x) {
#pragma unroll
  for (int o = 32; o > 0; o >>= 1) x = fmaxf(x, __shfl_xor(x, o, 64));
  return x;
}

// async global->LDS, 16B per lane (global_load_lds_dwordx4)
DEVINL void async16(ushort_t* lds, const ushort_t* g) {
  __builtin_amdgcn_global_load_lds(
      (__attribute__((address_space(1))) const unsigned int*)g,
      (__attribute__((address_space(3))) unsigned int*)lds, 16, 0, 0);
}

// ---------------- GroupNorm ----------------
// One block per (b,g): group data is contiguous 16ch*4096 = 65536 floats.
__global__ __launch_bounds__(256) void gn_stats_k(const float* __restrict__ x,
                                                  float* __restrict__ stats) {
  const int bg = blockIdx.x;
  const float4* base = (const float4*)(x + ((size_t)bg << 16));
  float s = 0.f, q = 0.f;
  for (int i = threadIdx.x; i < 16384; i += 256) {
    float4 f = base[i];
    s += f.x + f.y + f.z + f.w;
    q += f.x * f.x + f.y * f.y + f.z * f.z + f.w * f.w;
  }
  s = wred_sum(s);
  q = wred_sum(q);
  __shared__ float rs[4], rq[4];
  const int lane = threadIdx.x & 63, wid = threadIdx.x >> 6;
  if (lane == 0) { rs[wid] = s; rq[wid] = q; }
  __syncthreads();
  if (threadIdx.x == 0) {
    float S = rs[0] + rs[1] + rs[2] + rs[3];
    float Q = rq[0] + rq[1] + rq[2] + rq[3];
    float mean = S * (1.f / 65536.f);
    float var = Q * (1.f / 65536.f) - mean * mean;
    stats[2 * bg] = mean;
    stats[2 * bg + 1] = rsqrtf(var + 1e-5f);
  }
}

// normalize + transpose [B,C,N] fp32 -> h [B,N,C] bf16 via 32x32 LDS tiles
__global__ __launch_bounds__(256) void gn_apply_k(const float* __restrict__ x,
                                                  const float* __restrict__ stats,
                                                  const float* __restrict__ gs,
                                                  const float* __restrict__ gb,
                                                  ushort_t* __restrict__ h) {
  __shared__ ushort_t tile[32][33];
  const int bid = blockIdx.x;
  const int b = bid >> 11;
  const int r = bid & 2047;
  const int ct = r >> 7, nt = r & 127;
  const int c0 = ct << 5, n0 = nt << 5;
  const int tx = threadIdx.x & 31, ty = threadIdx.x >> 5;
#pragma unroll
  for (int i = 0; i < 4; ++i) {
    const int c = c0 + ty + i * 8;
    const float mean = stats[2 * (b * 32 + (c >> 4))];
    const float rstd = stats[2 * (b * 32 + (c >> 4)) + 1];
    const float xv = x[(((size_t)b * 512 + c) << 12) + n0 + tx];
    tile[ty + i * 8][tx] = f2bf((xv - mean) * rstd * gs[c] + gb[c]);
  }
  __syncthreads();
#pragma unroll
  for (int i = 0; i < 4; ++i) {
    const int n = n0 + ty + i * 8;
    h[(((size_t)b << 12) + n) * 512 + c0 + tx] = tile[tx][ty + i * 8];
  }
}

// fp32 -> bf16 weight convert (n = 262144 exactly, grid 1024x256)
__global__ __launch_bounds__(256) void cvt_k(const float* __restrict__ in,
                                             ushort_t* __restrict__ out) {
  const int i = blockIdx.x * 256 + threadIdx.x;
  out[i] = f2bf(in[i]);
}

// V [B,N,C] -> Vt [B,C,N] bf16, 32x32 LDS tiles
__global__ __launch_bounds__(256) void vtrans_k(const ushort_t* __restrict__ vin,
                                                ushort_t* __restrict__ vout) {
  __shared__ ushort_t tile[32][33];
  const int bid = blockIdx.x;
  const int b = bid >> 11;
  const int r = bid & 2047;
  const int nt = r >> 4, ct = r & 15;
  const int n0 = nt << 5, c0 = ct << 5;
  const int tx = threadIdx.x & 31, ty = threadIdx.x >> 5;
#pragma unroll
  for (int i = 0; i < 4; ++i)
    tile[ty + i * 8][tx] = vin[(((size_t)b << 12) + n0 + ty + i * 8) * 512 + c0 + tx];
  __syncthreads();
#pragma unroll
  for (int i = 0; i < 4; ++i)
    vout[(((size_t)b * 512 + c0 + ty + i * 8) << 12) + n0 + tx] = tile[tx][ty + i * 8];
}

// in-place row softmax: S fp32 [4096] -> P bf16 packed at row start (row stride 4096 fp32)
__global__ __launch_bounds__(256) void softmax_k(float* __restrict__ S) {
  const int row = blockIdx.x;
  float* rp = S + ((size_t)row << 12);
  const int t = threadIdx.x;
  float v[16];
  float mx = -3.4e38f;
#pragma unroll
  for (int i = 0; i < 16; ++i) {
    v[i] = rp[t + (i << 8)];
    mx = fmaxf(mx, v[i]);
  }
  mx = wred_max(mx);
  __shared__ float red[4];
  const int lane = t & 63, wid = t >> 6;
  if (lane == 0) red[wid] = mx;
  __syncthreads();
  mx = fmaxf(fmaxf(red[0], red[1]), fmaxf(red[2], red[3]));
  float s = 0.f;
#pragma unroll
  for (int i = 0; i < 16; ++i) {
    v[i] = __expf(v[i] - mx);
    s += v[i];
  }
  s = wred_sum(s);
  __syncthreads();
  if (lane == 0) red[wid] = s;
  __syncthreads();
  s = red[0] + red[1] + red[2] + red[3];
  const float inv = 1.f / s;
  ushort_t* pp = (ushort_t*)rp;
#pragma unroll
  for (int i = 0; i < 16; ++i) pp[t + (i << 8)] = f2bf(v[i] * inv);
}

// ---------------- NT GEMM: C[M,N] = A[M,K] * B[N,K]^T ----------------
// EPI 0: bf16 out (+optional bias). EPI 1: fp32 out * scale.
// EPI 2: fp32 transposed out: out[(b*512+col)*4096 + (row&4095)] = resid + acc + bias[col]
template <int BM, int BN, int EPI>
__global__ __launch_bounds__(256) void gemm_nt_k(
    const ushort_t* __restrict__ A, int lda, const ushort_t* __restrict__ B, int ldb,
    void* __restrict__ Cout, int ldc, const float* __restrict__ bias,
    const float* __restrict__ resid, float scale, int K) {
  constexpr int BK = 32;
  constexpr int WTM = BM / 2, WTN = BN / 2;
  constexpr int MI = WTM / 16, NI = WTN / 16;
  constexpr int AR = (BM * BK * 2) / 4096;  // 16B-chunk rounds for A (256 thr)
  constexpr int BR = (BN * BK * 2) / 4096;
  __shared__ ushort_t Als[BM * BK];
  __shared__ ushort_t Bls[BN * BK];
  const int tid = threadIdx.x;
  const int lane = tid & 63;
  const int wid = tid >> 6;
  const int quad = lane >> 4;
  const int r16 = lane & 15;
  const int wm = wid >> 1, wn = wid & 1;
  const int m0 = blockIdx.y * BM;
  const int n0 = blockIdx.x * BN;

  f32x4 acc[MI][NI] = {};

  for (int kt = 0; kt < K; kt += BK) {
#pragma unroll
    for (int r = 0; r < AR; ++r) {
      const int c = r * 256 + tid;
      async16(&Als[c << 3],
              A + (size_t)(m0 + (c >> 2)) * lda + kt + ((c & 3) << 3));
    }
#pragma unroll
    for (int r = 0; r < BR; ++r) {
      const int c = r * 256 + tid;
      async16(&Bls[c << 3],
              B + (size_t)(n0 + (c >> 2)) * ldb + kt + ((c & 3) << 3));
    }
    __syncthreads();  // drains vmcnt for global_load_lds (compiler emits full waitcnt)
    bf16x8 af[MI], bfr[NI];
#pragma unroll
    for (int mi = 0; mi < MI; ++mi)
      af[mi] = *reinterpret_cast<const bf16x8*>(
          &Als[(wm * WTM + mi * 16 + r16) * BK + quad * 8]);
#pragma unroll
    for (int ni = 0; ni < NI; ++ni)
      bfr[ni] = *reinterpret_cast<const bf16x8*>(
          &Bls[(wn * WTN + ni * 16 + r16) * BK + quad * 8]);
#pragma unroll
    for (int mi = 0; mi < MI; ++mi)
#pragma unroll
      for (int ni = 0; ni < NI; ++ni)
        acc[mi][ni] = __builtin_amdgcn_mfma_f32_16x16x32_bf16(
            af[mi], bfr[ni], acc[mi][ni], 0, 0, 0);
    __syncthreads();
  }

  const int mrow = m0 + wm * WTM;
  const int ncol = n0 + wn * WTN;
  if constexpr (EPI == 0) {
    ushort_t* C = (ushort_t*)Cout;
#pragma unroll
    for (int ni = 0; ni < NI; ++ni) {
      const int col = ncol + ni * 16 + r16;
      const float bvv = bias ? bias[col] : 0.f;
#pragma unroll
      for (int mi = 0; mi < MI; ++mi) {
        const int rowb = mrow + mi * 16 + quad * 4;
#pragma unroll
        for (int rr = 0; rr < 4; ++rr)
          C[(size_t)(rowb + rr) * ldc + col] = f2bf(acc[mi][ni][rr] + bvv);
      }
    }
  } else if constexpr (EPI == 1) {
    float* C = (float*)Cout;
#pragma unroll
    for (int ni = 0; ni < NI; ++ni) {
      const int col = ncol + ni * 16 + r16;
#pragma unroll
      for (int mi = 0; mi < MI; ++mi) {
        const int rowb = mrow + mi * 16 + quad * 4;
#pragma unroll
        for (int rr = 0; rr < 4; ++rr)
          C[(size_t)(rowb + rr) * ldc + col] = acc[mi][ni][rr] * scale;
      }
    }
  } else {
    float* C = (float*)Cout;
#pragma unroll
    for (int ni = 0; ni < NI; ++ni) {
      const int col = ncol + ni * 16 + r16;
      const float bvv = bias[col];
#pragma unroll
      for (int mi = 0; mi < MI; ++mi) {
        const int rowb = mrow + mi * 16 + quad * 4;
        const int bb = rowb >> 12;
        const int nl = rowb & 4095;
        const size_t base = (((size_t)bb * 512 + col) << 12) + nl;
#pragma unroll
        for (int rr = 0; rr < 4; ++rr)
          C[base + rr] = resid[base + rr] + acc[mi][ni][rr] + bvv;
      }
    }
  }
}

extern "C" void kernel_launch(void* const* d_in, const int* in_sizes, int n_in,
                              void* d_out, int out_size, void* d_ws, size_t ws_size,
                              hipStream_t stream) {
  const float* x  = (const float*)d_in[0];
  const float* gs = (const float*)d_in[1];
  const float* gb = (const float*)d_in[2];
  const float* wq = (const float*)d_in[3];
  const float* bq = (const float*)d_in[4];
  const float* wk = (const float*)d_in[5];
  const float* bk = (const float*)d_in[6];
  const float* wv = (const float*)d_in[7];
  const float* bv = (const float*)d_in[8];
  const float* wo = (const float*)d_in[9];
  const float* bo = (const float*)d_in[10];
  float* out = (float*)d_out;

  const size_t HNC = (size_t)4 * 4096 * 512;  // elems per bf16 activation buffer
  char* w = (char*)d_ws;
  float* stats   = (float*)w;     w += 4096;
  ushort_t* wqb  = (ushort_t*)w;  w += 512 * 512 * 2;
  ushort_t* wkb  = (ushort_t*)w;  w += 512 * 512 * 2;
  ushort_t* wvb  = (ushort_t*)w;  w += 512 * 512 * 2;
  ushort_t* wob  = (ushort_t*)w;  w += 512 * 512 * 2;
  ushort_t* h    = (ushort_t*)w;  w += HNC * 2;  // reused as O after projections
  ushort_t* q    = (ushort_t*)w;  w += HNC * 2;
  ushort_t* kk   = (ushort_t*)w;  w += HNC * 2;
  ushort_t* vtmp = (ushort_t*)w;  w += HNC * 2;
  ushort_t* vt   = (ushort_t*)w;  w += HNC * 2;
  float* S       = (float*)w;     w += (size_t)4096 * 4096 * 4;  // per-batch, reused

  gn_stats_k<<<128, 256, 0, stream>>>(x, stats);
  gn_apply_k<<<8192, 256, 0, stream>>>(x, stats, gs, gb, h);
  cvt_k<<<1024, 256, 0, stream>>>(wq, wqb);
  cvt_k<<<1024, 256, 0, stream>>>(wk, wkb);
  cvt_k<<<1024, 256, 0, stream>>>(wv, wvb);
  cvt_k<<<1024, 256, 0, stream>>>(wo, wob);

  // QKV projections: [16384,512] = h * W^T + b
  gemm_nt_k<128, 128, 0><<<dim3(4, 128), 256, 0, stream>>>(h, 512, wqb, 512, q, 512, bq, nullptr, 1.f, 512);
  gemm_nt_k<128, 128, 0><<<dim3(4, 128), 256, 0, stream>>>(h, 512, wkb, 512, kk, 512, bk, nullptr, 1.f, 512);
  gemm_nt_k<128, 128, 0><<<dim3(4, 128), 256, 0, stream>>>(h, 512, wvb, 512, vtmp, 512, bv, nullptr, 1.f, 512);
  vtrans_k<<<8192, 256, 0, stream>>>(vtmp, vt);

  const float sc = 0.044194173824159216f;  // 512^-0.5
  for (int b = 0; b < 4; ++b) {
    // S = (Q K^T) * sc   [4096,4096] fp32
    gemm_nt_k<128, 128, 1><<<dim3(32, 32), 256, 0, stream>>>(
        q + (size_t)b * 4096 * 512, 512, kk + (size_t)b * 4096 * 512, 512,
        S, 4096, nullptr, nullptr, sc, 512);
    softmax_k<<<4096, 256, 0, stream>>>(S);
    // O = P V : A = P bf16 (row stride 8192 elems), B = Vt [512,4096]
    gemm_nt_k<64, 128, 0><<<dim3(4, 64), 256, 0, stream>>>(
        (const ushort_t*)S, 8192, vt + (size_t)b * 512 * 4096, 4096,
        h + (size_t)b * 4096 * 512, 512, nullptr, nullptr, 1.f, 4096);
  }

  // out = x + O @ wo^T + bo, stored transposed back to [B,C,H,W]
  gemm_nt_k<128, 128, 2><<<dim3(4, 128), 256, 0, stream>>>(
      h, 512, wob, 512, out, 512, bo, x, 1.f, 512);
}

// Round 2
// 447.351 us; speedup vs baseline: 1.5379x; 1.5379x over previous
//
#include <hip/hip_runtime.h>
#include <cstdint>
#include <cstddef>

typedef unsigned short ushort_t;
typedef __attribute__((ext_vector_type(8))) __bf16 bf16x8;
typedef __attribute__((ext_vector_type(4))) float f32x4;

#define DEVINL __device__ __forceinline__

// fp32 -> bf16 round-to-nearest-even
DEVINL ushort_t f2bf(float f) {
  union { float f; unsigned u; } v; v.f = f;
  unsigned r = (v.u + 0x7fffu + ((v.u >> 16) & 1u)) >> 16;
  return (ushort_t)r;
}
DEVINL float bf2f(ushort_t u) {
  union { unsigned u; float f; } v; v.u = ((unsigned)u) << 16;
  return v.f;
}

DEVINL float wred_sum(float x) {
#pragma unroll
  for (int o = 32; o > 0; o >>= 1) x += __shfl_xor(x, o, 64);
  return x;
}
DEVINL float wred_max(float x) {
#pragma unroll
  for (int o = 32; o > 0; o >>= 1) x = fmaxf(x, __shfl_xor(x, o, 64));
  return x;
}

// async global->LDS, 16B per lane (global_load_lds_dwordx4)
DEVINL void async16(ushort_t* lds, const ushort_t* g) {
  __builtin_amdgcn_global_load_lds(
      (__attribute__((address_space(1))) const unsigned int*)g,
      (__attribute__((address_space(3))) unsigned int*)lds, 16, 0, 0);
}

// bank swizzle for 16B chunks: slot(row, chunk) = row*CPR + (chunk ^ fswz(row))
template <int CPR>
DEVINL int fswz(int r) {
  if constexpr (CPR == 4) return (r >> 2) & 3;   // row stride 64B
  else return r & 7;                             // CPR==8, row stride 128B
}

// ---------------- GroupNorm ----------------
__global__ __launch_bounds__(256) void gn_stats_k(const float* __restrict__ x,
                                                  float* __restrict__ stats) {
  const int bg = blockIdx.x;
  const float4* base = (const float4*)(x + ((size_t)bg << 16));
  float s = 0.f, q = 0.f;
  for (int i = threadIdx.x; i < 16384; i += 256) {
    float4 f = base[i];
    s += f.x + f.y + f.z + f.w;
    q += f.x * f.x + f.y * f.y + f.z * f.z + f.w * f.w;
  }
  s = wred_sum(s);
  q = wred_sum(q);
  __shared__ float rs[4], rq[4];
  const int lane = threadIdx.x & 63, wid = threadIdx.x >> 6;
  if (lane == 0) { rs[wid] = s; rq[wid] = q; }
  __syncthreads();
  if (threadIdx.x == 0) {
    float S = rs[0] + rs[1] + rs[2] + rs[3];
    float Q = rq[0] + rq[1] + rq[2] + rq[3];
    float mean = S * (1.f / 65536.f);
    float var = Q * (1.f / 65536.f) - mean * mean;
    stats[2 * bg] = mean;
    stats[2 * bg + 1] = rsqrtf(var + 1e-5f);
  }
}

// normalize + transpose [B,C,N] fp32 -> h [B,N,C] bf16 via 32x32 LDS tiles
__global__ __launch_bounds__(256) void gn_apply_k(const float* __restrict__ x,
                                                  const float* __restrict__ stats,
                                                  const float* __restrict__ gs,
                                                  const float* __restrict__ gb,
                                                  ushort_t* __restrict__ h) {
  __shared__ ushort_t tile[32][33];
  const int bid = blockIdx.x;
  const int b = bid >> 11;
  const int r = bid & 2047;
  const int ct = r >> 7, nt = r & 127;
  const int c0 = ct << 5, n0 = nt << 5;
  const int tx = threadIdx.x & 31, ty = threadIdx.x >> 5;
#pragma unroll
  for (int i = 0; i < 4; ++i) {
    const int c = c0 + ty + i * 8;
    const float mean = stats[2 * (b * 32 + (c >> 4))];
    const float rstd = stats[2 * (b * 32 + (c >> 4)) + 1];
    const float xv = x[(((size_t)b * 512 + c) << 12) + n0 + tx];
    tile[ty + i * 8][tx] = f2bf((xv - mean) * rstd * gs[c] + gb[c]);
  }
  __syncthreads();
#pragma unroll
  for (int i = 0; i < 4; ++i) {
    const int n = n0 + ty + i * 8;
    h[(((size_t)b << 12) + n) * 512 + c0 + tx] = tile[tx][ty + i * 8];
  }
}

// fp32 -> bf16 convert, all 4 weight matrices (4 x 262144) into one buffer
struct Ptr4 { const float* src[4]; };
__global__ __launch_bounds__(256) void cvt_all_k(Ptr4 s, ushort_t* __restrict__ dst) {
  const int i = blockIdx.x * 256 + threadIdx.x;
  const int m = i >> 18;
  dst[i] = f2bf(s.src[m][i & 262143]);
}

// batched in-place row softmax on bf16 S: 16384 rows of 4096
__global__ __launch_bounds__(256) void softmax_k(ushort_t* __restrict__ S) {
  uint4* rp = (uint4*)(S + ((size_t)blockIdx.x << 12));
  const int t = threadIdx.x;
  uint4 u0 = rp[t], u1 = rp[t + 256];
  float v[16];
  {
    const unsigned w[8] = {u0.x, u0.y, u0.z, u0.w, u1.x, u1.y, u1.z, u1.w};
#pragma unroll
    for (int j = 0; j < 8; ++j) {
      union { unsigned u; float f; } a, b;
      a.u = w[j] << 16;
      b.u = w[j] & 0xffff0000u;
      v[2 * j] = a.f;
      v[2 * j + 1] = b.f;
    }
  }
  float mx = v[0];
#pragma unroll
  for (int i = 1; i < 16; ++i) mx = fmaxf(mx, v[i]);
  mx = wred_max(mx);
  __shared__ float red[4];
  const int lane = t & 63, wid = t >> 6;
  if (lane == 0) red[wid] = mx;
  __syncthreads();
  mx = fmaxf(fmaxf(red[0], red[1]), fmaxf(red[2], red[3]));
  float s = 0.f;
#pragma unroll
  for (int i = 0; i < 16; ++i) {
    v[i] = __expf(v[i] - mx);
    s += v[i];
  }
  s = wred_sum(s);
  __syncthreads();
  if (lane == 0) red[wid] = s;
  __syncthreads();
  s = red[0] + red[1] + red[2] + red[3];
  const float inv = 1.f / s;
  unsigned w[8];
#pragma unroll
  for (int j = 0; j < 8; ++j)
    w[j] = (unsigned)f2bf(v[2 * j] * inv) | ((unsigned)f2bf(v[2 * j + 1] * inv) << 16);
  rp[t] = (uint4){w[0], w[1], w[2], w[3]};
  rp[t + 256] = (uint4){w[4], w[5], w[6], w[7]};
}

// ---------------- NT GEMM: C[M,N] = A[M,K] * B[N,K]^T ----------------
// EPI 0: bf16 out (PV, no bias). EPI 1: bf16 out * scale (scores).
// EPI 2: fp32 transposed out + resid + bias (final). EPI 3: QKV combined,
//        z=blockIdx.z picks weight/bias/dst; z==2 (V) writes transposed [C][N].
struct Ptr3 { const float* bias[3]; ushort_t* out[3]; };

template <int BM, int BN, int BK, int EPI>
__global__ __launch_bounds__(256) void gemm_nt_k(
    const ushort_t* __restrict__ A, int lda, const ushort_t* __restrict__ Bm, int ldb,
    void* __restrict__ Cout, int ldc, const float* __restrict__ bias,
    const float* __restrict__ resid, float scale, int K,
    size_t azs, size_t bzs, size_t czs, Ptr3 p3) {
  constexpr int CPR = BK / 8;                 // 16B chunks per row
  constexpr int WTM = BM / 2, WTN = BN / 2;
  constexpr int MI = WTM / 16, NI = WTN / 16;
  constexpr int AR = (BM * CPR) / 256;
  constexpr int BR = (BN * CPR) / 256;
  __shared__ ushort_t Als[BM * BK];
  __shared__ ushort_t Bls[BN * BK];
  const int tid = threadIdx.x;
  const int lane = tid & 63;
  const int wid = tid >> 6;
  const int quad = lane >> 4;
  const int r16 = lane & 15;
  const int wm = wid >> 1, wn = wid & 1;
  const int m0 = blockIdx.y * BM;
  const int n0 = blockIdx.x * BN;
  const int zb = blockIdx.z;

  A += azs * zb;
  Bm += bzs * zb;

  f32x4 acc[MI][NI] = {};

  for (int kt = 0; kt < K; kt += BK) {
#pragma unroll
    for (int r = 0; r < AR; ++r) {
      const int s = r * 256 + tid;
      const int row = s / CPR;
      const int q = (s % CPR) ^ fswz<CPR>(row);
      async16(&Als[s << 3], A + (size_t)(m0 + row) * lda + kt + (q << 3));
    }
#pragma unroll
    for (int r = 0; r < BR; ++r) {
      const int s = r * 256 + tid;
      const int row = s / CPR;
      const int q = (s % CPR) ^ fswz<CPR>(row);
      async16(&Bls[s << 3], Bm + (size_t)(n0 + row) * ldb + kt + (q << 3));
    }
    __syncthreads();
#pragma unroll
    for (int kf = 0; kf < BK / 32; ++kf) {
      bf16x8 af[MI], bfr[NI];
#pragma unroll
      for (int mi = 0; mi < MI; ++mi) {
        const int lr = wm * WTM + mi * 16 + r16;
        const int ch = kf * 4 + quad;
        af[mi] = *reinterpret_cast<const bf16x8*>(
            &Als[(lr * CPR + (ch ^ fswz<CPR>(lr))) << 3]);
      }
#pragma unroll
      for (int ni = 0; ni < NI; ++ni) {
        const int lr = wn * WTN + ni * 16 + r16;
        const int ch = kf * 4 + quad;
        bfr[ni] = *reinterpret_cast<const bf16x8*>(
            &Bls[(lr * CPR + (ch ^ fswz<CPR>(lr))) << 3]);
      }
#pragma unroll
      for (int mi = 0; mi < MI; ++mi)
#pragma unroll
        for (int ni = 0; ni < NI; ++ni)
          acc[mi][ni] = __builtin_amdgcn_mfma_f32_16x16x32_bf16(
              af[mi], bfr[ni], acc[mi][ni], 0, 0, 0);
    }
    __syncthreads();
  }

  const int mrow = m0 + wm * WTM;
  const int ncol = n0 + wn * WTN;
  if constexpr (EPI == 0) {
    ushort_t* C = (ushort_t*)Cout + czs * zb;
#pragma unroll
    for (int ni = 0; ni < NI; ++ni) {
      const int col = ncol + ni * 16 + r16;
#pragma unroll
      for (int mi = 0; mi < MI; ++mi) {
        const int rowb = mrow + mi * 16 + quad * 4;
#pragma unroll
        for (int rr = 0; rr < 4; ++rr)
          C[(size_t)(rowb + rr) * ldc + col] = f2bf(acc[mi][ni][rr]);
      }
    }
  } else if constexpr (EPI == 1) {
    ushort_t* C = (ushort_t*)Cout + czs * zb;
#pragma unroll
    for (int ni = 0; ni < NI; ++ni) {
      const int col = ncol + ni * 16 + r16;
#pragma unroll
      for (int mi = 0; mi < MI; ++mi) {
        const int rowb = mrow + mi * 16 + quad * 4;
#pragma unroll
        for (int rr = 0; rr < 4; ++rr)
          C[(size_t)(rowb + rr) * ldc + col] = f2bf(acc[mi][ni][rr] * scale);
      }
    }
  } else if constexpr (EPI == 2) {
    float* C = (float*)Cout;
#pragma unroll
    for (int ni = 0; ni < NI; ++ni) {
      const int col = ncol + ni * 16 + r16;
      const float bvv = bias[col];
#pragma unroll
      for (int mi = 0; mi < MI; ++mi) {
        const int rowb = mrow + mi * 16 + quad * 4;
        const int bb = rowb >> 12;
        const int nl = rowb & 4095;
        const size_t base = (((size_t)bb * 512 + col) << 12) + nl;
        const float4 rv = *(const float4*)&resid[base];
        float4 ov;
        ov.x = rv.x + acc[mi][ni][0] + bvv;
        ov.y = rv.y + acc[mi][ni][1] + bvv;
        ov.z = rv.z + acc[mi][ni][2] + bvv;
        ov.w = rv.w + acc[mi][ni][3] + bvv;
        *(float4*)&C[base] = ov;
      }
    }
  } else {  // EPI == 3, QKV
    const float* bz = p3.bias[zb];
    ushort_t* O = p3.out[zb];
    if (zb < 2) {
#pragma unroll
      for (int ni = 0; ni < NI; ++ni) {
        const int col = ncol + ni * 16 + r16;
        const float bvv = bz[col];
#pragma unroll
        for (int mi = 0; mi < MI; ++mi) {
          const int rowb = mrow + mi * 16 + quad * 4;
#pragma unroll
          for (int rr = 0; rr < 4; ++rr)
            O[(size_t)(rowb + rr) * 512 + col] = f2bf(acc[mi][ni][rr] + bvv);
        }
      }
    } else {  // V: write transposed [B,512ch,4096n], 4 n's packed per store
#pragma unroll
      for (int ni = 0; ni < NI; ++ni) {
        const int col = ncol + ni * 16 + r16;
        const float bvv = bz[col];
#pragma unroll
        for (int mi = 0; mi < MI; ++mi) {
          const int rowb = mrow + mi * 16 + quad * 4;
          const int bb = rowb >> 12;
          const int nn = rowb & 4095;
          ushort4 pk;
          pk.x = f2bf(acc[mi][ni][0] + bvv);
          pk.y = f2bf(acc[mi][ni][1] + bvv);
          pk.z = f2bf(acc[mi][ni][2] + bvv);
          pk.w = f2bf(acc[mi][ni][3] + bvv);
          *(ushort4*)&O[(((size_t)bb * 512 + col) << 12) + nn] = pk;
        }
      }
    }
  }
}

extern "C" void kernel_launch(void* const* d_in, const int* in_sizes, int n_in,
                              void* d_out, int out_size, void* d_ws, size_t ws_size,
                              hipStream_t stream) {
  const float* x  = (const float*)d_in[0];
  const float* gs = (const float*)d_in[1];
  const float* gb = (const float*)d_in[2];
  const float* wq = (const float*)d_in[3];
  const float* bq = (const float*)d_in[4];
  const float* wk = (const float*)d_in[5];
  const float* bk = (const float*)d_in[6];
  const float* wv = (const float*)d_in[7];
  const float* bv = (const float*)d_in[8];
  const float* wo = (const float*)d_in[9];
  const float* bo = (const float*)d_in[10];
  float* out = (float*)d_out;

  const size_t HNC = (size_t)4 * 4096 * 512;
  char* w = (char*)d_ws;
  float* stats  = (float*)w;    w += 4096;
  ushort_t* wb  = (ushort_t*)w; w += (size_t)4 * 262144 * 2;  // wq,wk,wv,wo bf16
  ushort_t* h   = (ushort_t*)w; w += HNC * 2;                 // GN out; reused as O
  ushort_t* q   = (ushort_t*)w; w += HNC * 2;
  ushort_t* kk  = (ushort_t*)w; w += HNC * 2;
  ushort_t* vt  = (ushort_t*)w; w += HNC * 2;                 // V transposed [B,C,N]
  ushort_t* S   = (ushort_t*)w; w += (size_t)4 * 4096 * 4096 * 2;  // bf16 scores/P

  Ptr3 eز{};
  gn_stats_k<<<128, 256, 0, stream>>>(x, stats);
  gn_apply_k<<<8192, 256, 0, stream>>>(x, stats, gs, gb, h);
  Ptr4 wsrc; wsrc.src[0] = wq; wsrc.src[1] = wk; wsrc.src[2] = wv; wsrc.src[3] = wo;
  cvt_all_k<<<4096, 256, 0, stream>>>(wsrc, wb);

  // QKV projections, batched over z (z picks weight/bias/output; V transposed)
  Ptr3 qkv;
  qkv.bias[0] = bq; qkv.bias[1] = bk; qkv.bias[2] = bv;
  qkv.out[0] = q; qkv.out[1] = kk; qkv.out[2] = vt;
  gemm_nt_k<128, 128, 32, 3><<<dim3(4, 128, 3), 256, 0, stream>>>(
      h, 512, wb, 512, nullptr, 0, nullptr, nullptr, 1.f, 512,
      0, 262144, 0, qkv);

  const float sc = 0.044194173824159216f;  // 512^-0.5
  Ptr3 e0{};
  // scores: S[b] = (Q K^T)*sc, bf16, batched over 4 batches
  gemm_nt_k<128, 128, 32, 1><<<dim3(32, 32, 4), 256, 0, stream>>>(
      q, 512, kk, 512, S, 4096, nullptr, nullptr, sc, 512,
      (size_t)4096 * 512, (size_t)4096 * 512, (size_t)4096 * 4096, e0);
  softmax_k<<<16384, 256, 0, stream>>>(S);
  // PV: O[b] = P V, batched; BK=64 to fatten each K-iteration
  gemm_nt_k<64, 128, 64, 0><<<dim3(4, 64, 4), 256, 0, stream>>>(
      S, 4096, vt, 4096, h, 512, nullptr, nullptr, 1.f, 4096,
      (size_t)4096 * 4096, (size_t)512 * 4096, (size_t)4096 * 512, e0);

  // out = x + O @ wo^T + bo, transposed back to [B,C,H,W]
  gemm_nt_k<128, 128, 32, 2><<<dim3(4, 128, 1), 256, 0, stream>>>(
      h, 512, wb + (size_t)3 * 262144, 512, out, 512, bo, x, 1.f, 512,
      0, 0, 0, e0);
}